// Round 9
// baseline (350.226 us; speedup 1.0000x reference)
//
#include <hip/hip_runtime.h>
#include <math.h>

// WavelengthDependentPropagation: out = ifft2( fft2(x) * H(lam_c, fy, fx) )
// B=8, C=3, H=W=1024.  Transposed-spectrum pipeline + bank-derotated T layout.
//   T layout: [img:24][x:1024][y:1024] complex, column x contiguous (8KB) BUT
//   its 64 y-blocks (16 complex each) barrel-rotated: block b at (b+x)&63.
//   -> K1's transposed line stores hit distinct DRAM banks (stride 8320B,
//      odd multiple of 128B) instead of aliasing at 8KB; K2/K3 unchanged
//      locality (contiguous 8KB per column, internally permuted).
//   K0: Htab[lam][kx][ky] (plain T orientation), pre-scaled by 2^-20
//   K1: 16 rows/block row FFT; LDS relayout; cooperative full-line T store
//   K2: one wave per column: global->regs -> FFT -> *H (regs) -> iFFT -> store
//   K3: full-line gather -> LDS -> row iFFT -> direct register store to planes

#define NIMG 24

__device__ __forceinline__ float2 cadd(float2 a, float2 b){ return make_float2(a.x+b.x, a.y+b.y); }
__device__ __forceinline__ float2 csub(float2 a, float2 b){ return make_float2(a.x-b.x, a.y-b.y); }
__device__ __forceinline__ float2 cmul(float2 a, float c, float s){ return make_float2(a.x*c - a.y*s, a.x*s + a.y*c); }

// swizzled byte offset within an 8KB column buffer for complex index j
__device__ __forceinline__ int SW(int j) {
    int b = j << 3;
    return b ^ (((b >> 7) & 7) << 4);
}

// ---------------- transfer function (mirrors the jnp fp32 chain exactly) ----
__device__ __forceinline__ float2 computeH(float lam, int ky, int kx) {
    int iy = (ky < 512) ? ky : ky - 1024;
    int ix = (kx < 512) ? kx : kx - 1024;
    const double recip = 1.0 / (1024.0 * 8e-06);
    float fy = (float)((double)iy * recip);
    float fx = (float)((double)ix * recip);
    float f2  = __fadd_rn(__fmul_rn(fy, fy), __fmul_rn(fx, fx));
    float l2  = __fmul_rn(lam, lam);
    float arg = __fsub_rn(1.0f, __fmul_rn(l2, f2));
    float2 h = make_float2(0.0f, 0.0f);
    if (arg > 0.0f) {
        float t  = __fdiv_rn(6.28318530717958647692f, lam);
        t        = __fmul_rn(t, 0.05f);
        float kz = __fmul_rn(t, __fsqrt_rn(arg));
        double s, c;
        sincos((double)kz, &s, &c);
        const float sc = 9.5367431640625e-07f;              // 2^-20
        h = make_float2((float)c * sc, (float)s * sc);
    }
    return h;
}

// Htab[c][kx][ky]  (plain T orientation: contiguous in ky, no rotation)
__global__ __launch_bounds__(256) void build_H_T(float2* __restrict__ Htab,
                                                 const float* __restrict__ wl) {
    int idx = blockIdx.x * 256 + threadIdx.x;
    int c   = idx >> 20;
    int rem = idx & 1048575;
    Htab[idx] = computeH(wl[c], rem & 1023, rem >> 10);
}

// ---------------- radix-4 butterflies ---------------------------------------
template<int SIGN>
__device__ __forceinline__ void dft4nt(float2& a0, float2& a1, float2& a2, float2& a3) {
    float2 t0 = cadd(a0, a2), t1 = csub(a0, a2);
    float2 t2 = cadd(a1, a3), t3 = csub(a1, a3);
    a0 = cadd(t0, t2);
    a2 = csub(t0, t2);
    a1 = make_float2(t1.x - SIGN * t3.y, t1.y + SIGN * t3.x);
    a3 = make_float2(t1.x + SIGN * t3.y, t1.y - SIGN * t3.x);
}
template<int SIGN>
__device__ __forceinline__ void dft4(float2& a0, float2& a1, float2& a2, float2& a3,
                                     float c1, float s1) {
    float c2 = c1*c1 - s1*s1, s2 = 2.f*c1*s1;
    float c3 = c2*c1 - s2*s1, s3 = s2*c1 + c2*s1;
    a1 = cmul(a1, c1, s1);
    a2 = cmul(a2, c2, s2);
    a3 = cmul(a3, c3, s3);
    dft4nt<SIGN>(a0, a1, a2, a3);
}

#define WSYNC() do { asm volatile("s_waitcnt lgkmcnt(0)" ::: "memory"); \
                     __builtin_amdgcn_wave_barrier(); } while (0)

// ---------------- modular 1024-pt wave-private FFT pieces (verified R1-R8) ---
// Register layout for round-A input and round-C output: v[a][b] = pos l+64(a+4b).

__device__ __forceinline__ void ldsToRegs(char* cb, int l, float2 (&v)[4][4]) {
    const int swzE = (((l >> 4)    ) & 7) << 4;
    const int swzO = (((l >> 4) + 4) & 7) << 4;
    char* rbE = cb + ((8 * l) ^ swzE);
    char* rbO = cb + ((8 * l) ^ swzO);
    #pragma unroll
    for (int k = 0; k < 4; ++k) {
        #pragma unroll
        for (int r = 0; r < 4; ++r) {
            const int tt = k + 4 * r;
            v[k][r] = *(const float2*)(((tt & 1) ? rbO : rbE) + 512 * tt);
        }
    }
}

template<int SIGN>
__device__ __forceinline__ void fftA(char* cb, int l, float2 (&v)[4][4]) {
    const float SPI8 = SIGN * 0.39269908169872415481f;     // pi/8
    #pragma unroll
    for (int k = 0; k < 4; ++k) dft4nt<SIGN>(v[k][0], v[k][1], v[k][2], v[k][3]);
    dft4nt<SIGN>(v[0][0], v[1][0], v[2][0], v[3][0]);
    #pragma unroll
    for (int q = 1; q < 4; ++q) {
        float s1, c1; __sincosf((float)q * SPI8, &s1, &c1);
        dft4<SIGN>(v[0][q], v[1][q], v[2][q], v[3][q], c1, s1);
    }
    char* wb = cb + 128 * l;
    const int L7 = l & 7;
    #pragma unroll
    for (int p = 0; p < 4; ++p) {
        *(float4*)(wb + 16 * ((2*p+0) ^ L7)) =
            make_float4(v[p][0].x, v[p][0].y, v[p][1].x, v[p][1].y);
        *(float4*)(wb + 16 * ((2*p+1) ^ L7)) =
            make_float4(v[p][2].x, v[p][2].y, v[p][3].x, v[p][3].y);
    }
}

template<int SIGN>
__device__ __forceinline__ void fftB(char* cb, int l) {
    const float SPI32  = SIGN * 0.09817477042468103870f;   // pi/32
    const float SPI128 = SIGN * 0.02454369260617025967f;   // pi/128
    const int swzE = (((l >> 4)    ) & 7) << 4;
    const int swzO = (((l >> 4) + 4) & 7) << 4;
    char* rbE = cb + ((8 * l) ^ swzE);
    char* rbO = cb + ((8 * l) ^ swzO);
    float2 v[4][4];
    #pragma unroll
    for (int k = 0; k < 4; ++k) {
        #pragma unroll
        for (int r = 0; r < 4; ++r) {
            const int tt = k + 4 * r;
            v[k][r] = *(const float2*)(((tt & 1) ? rbO : rbE) + 512 * tt);
        }
    }
    const int jm2 = l & 15;
    float s1, c1; __sincosf((float)jm2 * SPI32, &s1, &c1);
    #pragma unroll
    for (int k = 0; k < 4; ++k) dft4<SIGN>(v[k][0], v[k][1], v[k][2], v[k][3], c1, s1);
    const int lo8 = 8 * (l & 15);
    const int hi  = 2048 * (l >> 4);
    #pragma unroll
    for (int q = 0; q < 4; ++q) {
        float s1b, c1b; __sincosf((float)(jm2 + 16 * q) * SPI128, &s1b, &c1b);
        dft4<SIGN>(v[0][q], v[1][q], v[2][q], v[3][q], c1b, s1b);
        #pragma unroll
        for (int p = 0; p < 4; ++p) {
            const int K = ((q + 4 * p) & 7) << 4;
            *(float2*)(cb + (lo8 ^ K) + hi + 128 * q + 512 * p) = v[p][q];
        }
    }
}

template<int SIGN>
__device__ __forceinline__ void fftC(int l, float2 (&v)[4][4]) {
    const float SPI512 = SIGN * 0.00613592315154256492f;   // pi/512
    #pragma unroll
    for (int m = 0; m < 4; ++m) {
        float s1, c1; __sincosf((float)(l + 64 * m) * SPI512, &s1, &c1);
        dft4<SIGN>(v[m][0], v[m][1], v[m][2], v[m][3], c1, s1);
    }
}

// ---------------- K1: 16 rows/block + rotated full-line cooperative T store --
// 1024 thr = 16 waves, 128KB LDS.  Wave w FFTs row y0+w in its private 8KB.
// Relayout to addr(x,yi) = x*128 + ((yi*8) ^ sx(x)), then store one full 128B
// line per column, placed at rotated block (b0 + x) & 63 inside column x.
__global__ __launch_bounds__(1024) void k1_rows_T16(const float* __restrict__ xr,
                                                    const float* __restrict__ xi,
                                                    float2* __restrict__ T) {
    extern __shared__ char lds[];                 // 131072 bytes
    const int t = threadIdx.x, w = t >> 6, l = t & 63;
    const int img = blockIdx.x >> 6;
    const int b0  = blockIdx.x & 63;              // y-block index (y0 = b0*16)
    const int y0  = b0 << 4;
    const long long ib = (long long)img << 20;
    char* cb = lds + 8192 * w;                    // wave w owns row y0+w

    // direct global->reg load, round-A layout (256B/instr coalesced)
    const float* rr = xr + ib + (long long)(y0 + w) * 1024;
    const float* ri = xi + ib + (long long)(y0 + w) * 1024;
    float2 v[4][4];
    #pragma unroll
    for (int k = 0; k < 4; ++k) {
        #pragma unroll
        for (int r = 0; r < 4; ++r) {
            const int p = l + 64 * (k + 4 * r);
            v[k][r] = make_float2(rr[p], ri[p]);
        }
    }
    fftA<-1>(cb, l, v); WSYNC();
    fftB<-1>(cb, l);    WSYNC();
    ldsToRegs(cb, l, v);
    fftC<-1>(l, v);
    __syncthreads();                              // all waves done with scratch

    // relayout: element p of row w -> lds[p*128 + ((w*8) ^ sx(p))]
    {
        const int w8 = w << 3;
        #pragma unroll
        for (int m = 0; m < 4; ++m) {
            #pragma unroll
            for (int q = 0; q < 4; ++q) {
                const int p  = l + 64 * (m + 4 * q);
                const int sx = (((p >> 1) & 7) << 4) | (((p >> 4) & 1) << 3);
                *(float2*)(lds + p * 128 + (w8 ^ sx)) = v[m][q];
            }
        }
    }
    __syncthreads();

    // cooperative store: lanes {x group} x {j=0..7} cover one full 128B line
    // per column; line placed at rotated block (b0 + x) & 63.
    {
        const int j = l >> 3;
        const int xbase = (w << 3) + (l & 7);
        const bool sw = (w >> 1) & 1;             // == (x>>4)&1, wave-uniform
        #pragma unroll
        for (int i = 0; i < 8; ++i) {
            const int x   = xbase + (i << 7);
            const int s70 = ((x >> 1) & 7) << 4;
            float4 g = *(const float4*)(lds + x * 128 + ((16 * j) ^ s70));
            if (sw) g = make_float4(g.z, g.w, g.x, g.y);
            const int rb = (b0 + x) & 63;         // rotated y-block
            *(float4*)(T + ib + (long long)x * 1024 + (rb << 4) + 2 * j) = g;
        }
    }
}

// ---------------- K2: column pass, registers end-to-end, rotated indexing ----
// 256 thr = 4 waves, one column per wave, 32KB LDS, zero block barriers.
__global__ __launch_bounds__(256, 4) void k2_cols_H(float2* __restrict__ T,
                                                    const float2* __restrict__ Htab,
                                                    const float* __restrict__ wl) {
    __shared__ float4 ldsb[2048];                 // 32KB
    char* lds = (char*)ldsb;
    const int t = threadIdx.x, w = t >> 6, l = t & 63;
    const int img = blockIdx.x >> 8;
    const int x   = ((blockIdx.x & 255) << 2) + w;
    const int lamIdx = img % 3;
    char* cb = lds + 8192 * w;
    float2* col = T + ((long long)img << 20) + (long long)x * 1024;

    // rotated in-column index for y = l + 64*tt: block (l>>4)+4tt -> +x mod 64
    const int xl15 = l & 15, lhi = l >> 4;
    #define CIDX(tt) (((((lhi) + 4 * (tt) + x) & 63) << 4) + xl15)

    // global -> regs in round-A layout (contiguous 8KB span, permuted inside)
    float2 v[4][4];
    #pragma unroll
    for (int k = 0; k < 4; ++k) {
        #pragma unroll
        for (int r = 0; r < 4; ++r)
            v[k][r] = col[CIDX(k + 4 * r)];
    }
    fftA<-1>(cb, l, v); WSYNC();
    fftB<-1>(cb, l);    WSYNC();

    // H loads issued here (cover latency under round C); H table NOT rotated
    float2 h[4][4];
    if (Htab) {
        const float2* hrow = Htab + ((long long)lamIdx << 20) + (long long)x * 1024;
        #pragma unroll
        for (int m = 0; m < 4; ++m) {
            #pragma unroll
            for (int q = 0; q < 4; ++q)
                h[m][q] = hrow[l + 64 * (m + 4 * q)];
        }
    } else {
        const float lam = wl[lamIdx];
        #pragma unroll
        for (int m = 0; m < 4; ++m) {
            #pragma unroll
            for (int q = 0; q < 4; ++q)
                h[m][q] = computeH(lam, l + 64 * (m + 4 * q), x);
        }
    }

    ldsToRegs(cb, l, v);
    fftC<-1>(l, v);

    // *H in registers
    #pragma unroll
    for (int m = 0; m < 4; ++m) {
        #pragma unroll
        for (int q = 0; q < 4; ++q) {
            float2 a = v[m][q], hh = h[m][q];
            v[m][q] = make_float2(a.x * hh.x - a.y * hh.y, a.x * hh.y + a.y * hh.x);
        }
    }
    WSYNC();   // order C-reads before inverse A-writes

    fftA<1>(cb, l, v); WSYNC();
    fftB<1>(cb, l);    WSYNC();
    ldsToRegs(cb, l, v);
    fftC<1>(l, v);

    // store back with the same rotated indexing
    #pragma unroll
    for (int m = 0; m < 4; ++m) {
        #pragma unroll
        for (int q = 0; q < 4; ++q)
            col[CIDX(m + 4 * q)] = v[m][q];
    }
    #undef CIDX
}

// ---------------- K3: rotated full-line gather + row iFFT -> planes ----------
__global__ __launch_bounds__(1024) void k3_irows_T16(const float2* __restrict__ T,
                                                     float* __restrict__ outr,
                                                     float* __restrict__ outi) {
    extern __shared__ char lds[];                 // 131072 bytes
    const int t = threadIdx.x, w = t >> 6, l = t & 63;
    const int img = blockIdx.x >> 6;
    const int b0  = blockIdx.x & 63;
    const int y0  = b0 << 4;
    const long long ib = (long long)img << 20;

    // gather: thread t = column t; its y-window is the single rotated block
    {
        const int rb = (b0 + t) & 63;
        const float4* src = (const float4*)(T + ib + (long long)t * 1024 + (rb << 4));
        const int sx = SW(t);
        #pragma unroll
        for (int p = 0; p < 8; ++p) {
            float4 g = src[p];
            *(float2*)(lds + 8192 * (2 * p)     + sx) = make_float2(g.x, g.y);
            *(float2*)(lds + 8192 * (2 * p + 1) + sx) = make_float2(g.z, g.w);
        }
    }
    __syncthreads();

    char* cb = lds + 8192 * w;                    // wave w owns row y0+w
    float2 v[4][4];
    ldsToRegs(cb, l, v);
    fftA<1>(cb, l, v); WSYNC();
    fftB<1>(cb, l);    WSYNC();
    ldsToRegs(cb, l, v);
    fftC<1>(l, v);

    // direct store to planes (256B/instr coalesced dword stores)
    float* pr = outr + ib + (long long)(y0 + w) * 1024;
    float* pi = outi + ib + (long long)(y0 + w) * 1024;
    #pragma unroll
    for (int m = 0; m < 4; ++m) {
        #pragma unroll
        for (int q = 0; q < 4; ++q) {
            const int p = l + 64 * (m + 4 * q);
            pr[p] = v[m][q].x;
            pi[p] = v[m][q].y;
        }
    }
}

// ---------------- launch ------------------------------------------------------
extern "C" void kernel_launch(void* const* d_in, const int* in_sizes, int n_in,
                              void* d_out, int out_size, void* d_ws, size_t ws_size,
                              hipStream_t stream) {
    const float* xr = (const float*)d_in[0];
    const float* xi = (const float*)d_in[1];
    const float* wl = (const float*)d_in[2];
    float* out = (float*)d_out;

    const size_t planeElems = (size_t)NIMG * 1024 * 1024;          // 24M
    float2* wsC = (float2*)d_ws;                                   // 192 MB
    const size_t needC = planeElems * sizeof(float2);
    const size_t needH = (size_t)3 * 1024 * 1024 * sizeof(float2); // 24 MB
    float2* Htab = nullptr;
    if (ws_size >= needC + needH) {
        Htab = (float2*)((char*)d_ws + needC);
        build_H_T<<<12288, 256, 0, stream>>>(Htab, wl);
    }
    k1_rows_T16<<<NIMG * 64, 1024, 131072, stream>>>(xr, xi, wsC);
    k2_cols_H<<<NIMG * 256, 256, 0, stream>>>(wsC, Htab, wl);
    k3_irows_T16<<<NIMG * 64, 1024, 131072, stream>>>(wsC, out, out + planeElems);
}

// Round 10
// 334.395 us; speedup vs baseline: 1.0473x; 1.0473x over previous
//
#include <hip/hip_runtime.h>
#include <math.h>

// WavelengthDependentPropagation: out = ifft2( fft2(x) * H(lam_c, fy, fx) )
// B=8, C=3, H=W=1024.  Tile-major scratch: every kernel's WRITES contiguous.
//   A layout: [img:24][b:64][x:1024][yi:16] complex  (b = y>>4, yi = y&15)
//     K1 block (img,b): row-FFT 16 rows -> one contiguous 128KB store.
//     K2 wave (img,x):  reads/writes column x = 64 chunks x 128B @16KB stride
//                       (strided READS tolerable; writes in-place, clustered
//                        by 8 adjacent-column waves per block).
//     K3 block (img,b): contiguous 128KB gather -> 16 row iFFTs -> planes.
//   K0: Htab[lam][kx][ky] (T orientation), pre-scaled by 2^-20.
//   K2 iterates images in REVERSE so its first reads hit K1's freshest
//   (L3-resident) output; K3 runs forward from where K2 finished.

#define NIMG 24

__device__ __forceinline__ float2 cadd(float2 a, float2 b){ return make_float2(a.x+b.x, a.y+b.y); }
__device__ __forceinline__ float2 csub(float2 a, float2 b){ return make_float2(a.x-b.x, a.y-b.y); }
__device__ __forceinline__ float2 cmul(float2 a, float c, float s){ return make_float2(a.x*c - a.y*s, a.x*s + a.y*c); }

// ---------------- transfer function (mirrors the jnp fp32 chain exactly) ----
__device__ __forceinline__ float2 computeH(float lam, int ky, int kx) {
    int iy = (ky < 512) ? ky : ky - 1024;
    int ix = (kx < 512) ? kx : kx - 1024;
    const double recip = 1.0 / (1024.0 * 8e-06);
    float fy = (float)((double)iy * recip);
    float fx = (float)((double)ix * recip);
    float f2  = __fadd_rn(__fmul_rn(fy, fy), __fmul_rn(fx, fx));
    float l2  = __fmul_rn(lam, lam);
    float arg = __fsub_rn(1.0f, __fmul_rn(l2, f2));
    float2 h = make_float2(0.0f, 0.0f);
    if (arg > 0.0f) {
        float t  = __fdiv_rn(6.28318530717958647692f, lam);
        t        = __fmul_rn(t, 0.05f);
        float kz = __fmul_rn(t, __fsqrt_rn(arg));
        double s, c;
        sincos((double)kz, &s, &c);
        const float sc = 9.5367431640625e-07f;              // 2^-20
        h = make_float2((float)c * sc, (float)s * sc);
    }
    return h;
}

// Htab[c][kx][ky]  (T orientation: contiguous in ky)
__global__ __launch_bounds__(256) void build_H_T(float2* __restrict__ Htab,
                                                 const float* __restrict__ wl) {
    int idx = blockIdx.x * 256 + threadIdx.x;
    int c   = idx >> 20;
    int rem = idx & 1048575;
    Htab[idx] = computeH(wl[c], rem & 1023, rem >> 10);
}

// ---------------- radix-4 butterflies ---------------------------------------
template<int SIGN>
__device__ __forceinline__ void dft4nt(float2& a0, float2& a1, float2& a2, float2& a3) {
    float2 t0 = cadd(a0, a2), t1 = csub(a0, a2);
    float2 t2 = cadd(a1, a3), t3 = csub(a1, a3);
    a0 = cadd(t0, t2);
    a2 = csub(t0, t2);
    a1 = make_float2(t1.x - SIGN * t3.y, t1.y + SIGN * t3.x);
    a3 = make_float2(t1.x + SIGN * t3.y, t1.y - SIGN * t3.x);
}
template<int SIGN>
__device__ __forceinline__ void dft4(float2& a0, float2& a1, float2& a2, float2& a3,
                                     float c1, float s1) {
    float c2 = c1*c1 - s1*s1, s2 = 2.f*c1*s1;
    float c3 = c2*c1 - s2*s1, s3 = s2*c1 + c2*s1;
    a1 = cmul(a1, c1, s1);
    a2 = cmul(a2, c2, s2);
    a3 = cmul(a3, c3, s3);
    dft4nt<SIGN>(a0, a1, a2, a3);
}

#define WSYNC() do { asm volatile("s_waitcnt lgkmcnt(0)" ::: "memory"); \
                     __builtin_amdgcn_wave_barrier(); } while (0)

// ---------------- modular 1024-pt wave-private FFT pieces (verified R1-R9) ---
// Register layout for round-A input and round-C output: v[a][b] = pos l+64(a+4b).

__device__ __forceinline__ void ldsToRegs(char* cb, int l, float2 (&v)[4][4]) {
    const int swzE = (((l >> 4)    ) & 7) << 4;
    const int swzO = (((l >> 4) + 4) & 7) << 4;
    char* rbE = cb + ((8 * l) ^ swzE);
    char* rbO = cb + ((8 * l) ^ swzO);
    #pragma unroll
    for (int k = 0; k < 4; ++k) {
        #pragma unroll
        for (int r = 0; r < 4; ++r) {
            const int tt = k + 4 * r;
            v[k][r] = *(const float2*)(((tt & 1) ? rbO : rbE) + 512 * tt);
        }
    }
}

template<int SIGN>
__device__ __forceinline__ void fftA(char* cb, int l, float2 (&v)[4][4]) {
    const float SPI8 = SIGN * 0.39269908169872415481f;     // pi/8
    #pragma unroll
    for (int k = 0; k < 4; ++k) dft4nt<SIGN>(v[k][0], v[k][1], v[k][2], v[k][3]);
    dft4nt<SIGN>(v[0][0], v[1][0], v[2][0], v[3][0]);
    #pragma unroll
    for (int q = 1; q < 4; ++q) {
        float s1, c1; __sincosf((float)q * SPI8, &s1, &c1);
        dft4<SIGN>(v[0][q], v[1][q], v[2][q], v[3][q], c1, s1);
    }
    char* wb = cb + 128 * l;
    const int L7 = l & 7;
    #pragma unroll
    for (int p = 0; p < 4; ++p) {
        *(float4*)(wb + 16 * ((2*p+0) ^ L7)) =
            make_float4(v[p][0].x, v[p][0].y, v[p][1].x, v[p][1].y);
        *(float4*)(wb + 16 * ((2*p+1) ^ L7)) =
            make_float4(v[p][2].x, v[p][2].y, v[p][3].x, v[p][3].y);
    }
}

template<int SIGN>
__device__ __forceinline__ void fftB(char* cb, int l) {
    const float SPI32  = SIGN * 0.09817477042468103870f;   // pi/32
    const float SPI128 = SIGN * 0.02454369260617025967f;   // pi/128
    const int swzE = (((l >> 4)    ) & 7) << 4;
    const int swzO = (((l >> 4) + 4) & 7) << 4;
    char* rbE = cb + ((8 * l) ^ swzE);
    char* rbO = cb + ((8 * l) ^ swzO);
    float2 v[4][4];
    #pragma unroll
    for (int k = 0; k < 4; ++k) {
        #pragma unroll
        for (int r = 0; r < 4; ++r) {
            const int tt = k + 4 * r;
            v[k][r] = *(const float2*)(((tt & 1) ? rbO : rbE) + 512 * tt);
        }
    }
    const int jm2 = l & 15;
    float s1, c1; __sincosf((float)jm2 * SPI32, &s1, &c1);
    #pragma unroll
    for (int k = 0; k < 4; ++k) dft4<SIGN>(v[k][0], v[k][1], v[k][2], v[k][3], c1, s1);
    const int lo8 = 8 * (l & 15);
    const int hi  = 2048 * (l >> 4);
    #pragma unroll
    for (int q = 0; q < 4; ++q) {
        float s1b, c1b; __sincosf((float)(jm2 + 16 * q) * SPI128, &s1b, &c1b);
        dft4<SIGN>(v[0][q], v[1][q], v[2][q], v[3][q], c1b, s1b);
        #pragma unroll
        for (int p = 0; p < 4; ++p) {
            const int K = ((q + 4 * p) & 7) << 4;
            *(float2*)(cb + (lo8 ^ K) + hi + 128 * q + 512 * p) = v[p][q];
        }
    }
}

template<int SIGN>
__device__ __forceinline__ void fftC(int l, float2 (&v)[4][4]) {
    const float SPI512 = SIGN * 0.00613592315154256492f;   // pi/512
    #pragma unroll
    for (int m = 0; m < 4; ++m) {
        float s1, c1; __sincosf((float)(l + 64 * m) * SPI512, &s1, &c1);
        dft4<SIGN>(v[m][0], v[m][1], v[m][2], v[m][3], c1, s1);
    }
}

// Relayout LDS mapping (verified R8): row w, position p ->
//   byte p*128 + ((8*w) ^ sx(p)),  sx(p) = ((p>>1)&7)<<4 | ((p>>4)&1)<<3.
// 16B granule view: slot (x, yj) at x*128 + (16*yj ^ ((x>>1)&7)<<4) holds rows
// (2yj, 2yj+1), pair-swapped iff (x>>4)&1.

// ---------------- K1: 16 rows/block row FFT -> contiguous 128KB A store ------
__global__ __launch_bounds__(1024) void k1_rows_A(const float* __restrict__ xr,
                                                  const float* __restrict__ xi,
                                                  float2* __restrict__ A) {
    extern __shared__ char lds[];                 // 131072 bytes
    const int t = threadIdx.x, w = t >> 6, l = t & 63;
    const int img = blockIdx.x >> 6;
    const int b0  = blockIdx.x & 63;
    const int y0  = b0 << 4;
    const long long ib = (long long)img << 20;
    char* cb = lds + 8192 * w;                    // wave w owns row y0+w

    // direct global->reg load, round-A layout (256B/instr coalesced)
    const float* rr = xr + ib + (long long)(y0 + w) * 1024;
    const float* ri = xi + ib + (long long)(y0 + w) * 1024;
    float2 v[4][4];
    #pragma unroll
    for (int k = 0; k < 4; ++k) {
        #pragma unroll
        for (int r = 0; r < 4; ++r) {
            const int p = l + 64 * (k + 4 * r);
            v[k][r] = make_float2(rr[p], ri[p]);
        }
    }
    fftA<-1>(cb, l, v); WSYNC();
    fftB<-1>(cb, l);    WSYNC();
    ldsToRegs(cb, l, v);
    fftC<-1>(l, v);
    __syncthreads();                              // all waves done with scratch

    // relayout: element p of row w -> lds[p*128 + ((w*8) ^ sx(p))]
    {
        const int w8 = w << 3;
        #pragma unroll
        for (int m = 0; m < 4; ++m) {
            #pragma unroll
            for (int q = 0; q < 4; ++q) {
                const int p  = l + 64 * (m + 4 * q);
                const int sx = (((p >> 1) & 7) << 4) | (((p >> 4) & 1) << 3);
                *(float2*)(lds + p * 128 + (w8 ^ sx)) = v[m][q];
            }
        }
    }
    __syncthreads();

    // contiguous store of the whole 128KB tile: A[img][b0][x][yi]
    // float4 fidx covers (x = fidx>>3, yi = 2*(fidx&7) .. +1); per wave-instr
    // the 64 lanes tile a contiguous 1KB.
    {
        float4* dst = (float4*)(A + ib + (long long)b0 * 16384);
        #pragma unroll
        for (int i = 0; i < 8; ++i) {
            const int fidx = t + 1024 * i;
            const int x  = fidx >> 3, yj = fidx & 7;
            const int s70 = ((x >> 1) & 7) << 4;
            float4 g = *(const float4*)(lds + x * 128 + ((16 * yj) ^ s70));
            if ((x >> 4) & 1) g = make_float4(g.z, g.w, g.x, g.y);
            dst[fidx] = g;
        }
    }
}

// ---------------- K2: column pass in A layout, in place, image-reversed ------
// 512 thr = 8 waves, 8 adjacent columns per block, 64KB LDS, no block barriers.
__global__ __launch_bounds__(512, 4) void k2_cols_H(float2* __restrict__ A,
                                                    const float2* __restrict__ Htab,
                                                    const float* __restrict__ wl) {
    __shared__ float4 ldsb[4096];                 // 64KB
    char* lds = (char*)ldsb;
    const int t = threadIdx.x, w = t >> 6, l = t & 63;
    const int img = (NIMG - 1) - (blockIdx.x >> 7);      // reversed
    const int x   = ((blockIdx.x & 127) << 3) + w;
    const int lamIdx = img % 3;
    char* cb = lds + 8192 * w;

    // column x in A layout: y = l + 64*tt -> chunk b = (l>>4)+4tt, yi = l&15
    float2* colA = A + ((long long)img << 20) + x * 16 + (l & 15);
    const int bl = (l >> 4) << 14;                // (l>>4) * 16384

    float2 v[4][4];
    #pragma unroll
    for (int k = 0; k < 4; ++k) {
        #pragma unroll
        for (int r = 0; r < 4; ++r)
            v[k][r] = colA[bl + (k + 4 * r) * 65536];
    }
    fftA<-1>(cb, l, v); WSYNC();
    fftB<-1>(cb, l);    WSYNC();

    // H loads issued here (cover latency under round C)
    float2 h[4][4];
    if (Htab) {
        const float2* hrow = Htab + ((long long)lamIdx << 20) + (long long)x * 1024;
        #pragma unroll
        for (int m = 0; m < 4; ++m) {
            #pragma unroll
            for (int q = 0; q < 4; ++q)
                h[m][q] = hrow[l + 64 * (m + 4 * q)];
        }
    } else {
        const float lam = wl[lamIdx];
        #pragma unroll
        for (int m = 0; m < 4; ++m) {
            #pragma unroll
            for (int q = 0; q < 4; ++q)
                h[m][q] = computeH(lam, l + 64 * (m + 4 * q), x);
        }
    }

    ldsToRegs(cb, l, v);
    fftC<-1>(l, v);

    // *H in registers
    #pragma unroll
    for (int m = 0; m < 4; ++m) {
        #pragma unroll
        for (int q = 0; q < 4; ++q) {
            float2 a = v[m][q], hh = h[m][q];
            v[m][q] = make_float2(a.x * hh.x - a.y * hh.y, a.x * hh.y + a.y * hh.x);
        }
    }
    WSYNC();   // order C-reads before inverse A-writes

    fftA<1>(cb, l, v); WSYNC();
    fftB<1>(cb, l);    WSYNC();
    ldsToRegs(cb, l, v);
    fftC<1>(l, v);

    // in-place store, same chunked addresses
    #pragma unroll
    for (int m = 0; m < 4; ++m) {
        #pragma unroll
        for (int q = 0; q < 4; ++q)
            colA[bl + (m + 4 * q) * 65536] = v[m][q];
    }
}

// ---------------- K3: contiguous 128KB gather -> 16 row iFFTs -> planes ------
__global__ __launch_bounds__(1024) void k3_irows_A(const float2* __restrict__ A,
                                                   float* __restrict__ outr,
                                                   float* __restrict__ outi) {
    extern __shared__ char lds[];                 // 131072 bytes
    const int t = threadIdx.x, w = t >> 6, l = t & 63;
    const int img = blockIdx.x >> 6;
    const int b0  = blockIdx.x & 63;
    const int y0  = b0 << 4;
    const long long ib = (long long)img << 20;

    // contiguous gather of the 128KB tile -> relayout LDS (inverse of K1 store)
    {
        const float4* src = (const float4*)(A + ib + (long long)b0 * 16384);
        #pragma unroll
        for (int i = 0; i < 8; ++i) {
            const int fidx = t + 1024 * i;
            const int x  = fidx >> 3, yj = fidx & 7;
            const int s70 = ((x >> 1) & 7) << 4;
            float4 g = src[fidx];
            if ((x >> 4) & 1) g = make_float4(g.z, g.w, g.x, g.y);
            *(float4*)(lds + x * 128 + ((16 * yj) ^ s70)) = g;
        }
    }
    __syncthreads();

    // wave w reads row y0+w into round-A register layout
    float2 v[4][4];
    {
        const int w8 = w << 3;
        #pragma unroll
        for (int m = 0; m < 4; ++m) {
            #pragma unroll
            for (int q = 0; q < 4; ++q) {
                const int p  = l + 64 * (m + 4 * q);
                const int sx = (((p >> 1) & 7) << 4) | (((p >> 4) & 1) << 3);
                v[m][q] = *(const float2*)(lds + p * 128 + (w8 ^ sx));
            }
        }
    }
    __syncthreads();                              // relayout fully read

    char* cb = lds + 8192 * w;
    fftA<1>(cb, l, v); WSYNC();
    fftB<1>(cb, l);    WSYNC();
    ldsToRegs(cb, l, v);
    fftC<1>(l, v);

    // direct store to planes (256B/instr coalesced dword stores)
    float* pr = outr + ib + (long long)(y0 + w) * 1024;
    float* pi = outi + ib + (long long)(y0 + w) * 1024;
    #pragma unroll
    for (int m = 0; m < 4; ++m) {
        #pragma unroll
        for (int q = 0; q < 4; ++q) {
            const int p = l + 64 * (m + 4 * q);
            pr[p] = v[m][q].x;
            pi[p] = v[m][q].y;
        }
    }
}

// ---------------- launch ------------------------------------------------------
extern "C" void kernel_launch(void* const* d_in, const int* in_sizes, int n_in,
                              void* d_out, int out_size, void* d_ws, size_t ws_size,
                              hipStream_t stream) {
    const float* xr = (const float*)d_in[0];
    const float* xi = (const float*)d_in[1];
    const float* wl = (const float*)d_in[2];
    float* out = (float*)d_out;

    const size_t planeElems = (size_t)NIMG * 1024 * 1024;          // 24M
    float2* A = (float2*)d_ws;                                     // 192 MB
    const size_t needA = planeElems * sizeof(float2);
    const size_t needH = (size_t)3 * 1024 * 1024 * sizeof(float2); // 24 MB
    float2* Htab = nullptr;
    if (ws_size >= needA + needH) {
        Htab = (float2*)((char*)d_ws + needA);
        build_H_T<<<12288, 256, 0, stream>>>(Htab, wl);
    }
    k1_rows_A<<<NIMG * 64, 1024, 131072, stream>>>(xr, xi, A);
    k2_cols_H<<<NIMG * 128, 512, 0, stream>>>(A, Htab, wl);
    k3_irows_A<<<NIMG * 64, 1024, 131072, stream>>>(A, out, out + planeElems);
}